// Round 1
// baseline (2020.891 us; speedup 1.0000x reference)
//
#include <hip/hip_runtime.h>

typedef unsigned short u16;
typedef unsigned int u32;

#define T_ 2048
#define B_ 16
#define D_ 1024
constexpr int MM = T_ * B_;     // 32768 GEMM rows
constexpr int KK = D_;          // 1024
constexpr int NN = 2 * D_;      // 2048 (alpha cols | v cols)
constexpr int BD = B_ * D_;     // 16384
constexpr int BM = 128, BN = 128, BK = 32;

typedef __bf16 bf16x8 __attribute__((ext_vector_type(8)));
typedef float f32x4 __attribute__((ext_vector_type(4)));

// ---------------- split fp32 -> bf16 hi/lo (truncation; lo corrects hi) ----
__device__ inline void split1(float f, u16& h, u16& l) {
    u32 u = __float_as_uint(f);
    h = (u16)(u >> 16);
    float fh = __uint_as_float(u & 0xffff0000u);
    float r = f - fh;                   // exact (low mantissa bits)
    l = (u16)(__float_as_uint(r) >> 16);
}

__global__ __launch_bounds__(256) void split_kernel(
    const float* __restrict__ src, u16* __restrict__ hi, u16* __restrict__ lo, int n4)
{
    int i = blockIdx.x * 256 + threadIdx.x;
    if (i >= n4) return;
    float4 v = ((const float4*)src)[i];
    u16 h0, h1, h2, h3, l0, l1, l2, l3;
    split1(v.x, h0, l0); split1(v.y, h1, l1);
    split1(v.z, h2, l2); split1(v.w, h3, l3);
    ushort4 hv; hv.x = h0; hv.y = h1; hv.z = h2; hv.w = h3;
    ushort4 lv; lv.x = l0; lv.y = l1; lv.z = l2; lv.w = l3;
    ((ushort4*)hi)[i] = hv;
    ((ushort4*)lo)[i] = lv;
}

// ---------------- fused dual GEMM: [32768,1024] x [2048,1024]^T ------------
// n<1024 -> sigmoid(.+b_alpha) = alpha  -> h region slot t+1
// n>=1024 -> tanh(.+b_v)       = v_raw  -> out region
__global__ __launch_bounds__(256) void gemm_dual(
    const u16* __restrict__ xhi, const u16* __restrict__ xlo,
    const u16* __restrict__ whi, const u16* __restrict__ wlo,
    const float* __restrict__ ba, const float* __restrict__ bv,
    float* __restrict__ out_ptr, float* __restrict__ h_ptr)
{
    __shared__ u16 Ah[BM][BK];
    __shared__ u16 Al[BM][BK];
    __shared__ u16 Bh[BN][BK];
    __shared__ u16 Bl[BN][BK];

    const int tid  = threadIdx.x;
    const int m0   = blockIdx.y * BM;
    const int n0   = blockIdx.x * BN;
    const int wave = tid >> 6, lane = tid & 63;
    const int wm = (wave & 1) << 6;     // wave's 64-row region
    const int wn = (wave >> 1) << 6;    // wave's 64-col region
    const int fm = lane & 15, quad = lane >> 4;
    const int srow = tid >> 2;          // 0..63 staging row
    const int scc  = (tid & 3) << 3;    // staging col offset (elements)

    f32x4 acc[4][4] = {};

    for (int k0 = 0; k0 < KK; k0 += BK) {
        #pragma unroll
        for (int hh = 0; hh < 2; ++hh) {
            int row = srow + hh * 64;
            size_t ga = (size_t)(m0 + row) * KK + k0 + scc;
            size_t gb = (size_t)(n0 + row) * KK + k0 + scc;
            *(uint4*)&Ah[row][scc] = *(const uint4*)(xhi + ga);
            *(uint4*)&Al[row][scc] = *(const uint4*)(xlo + ga);
            *(uint4*)&Bh[row][scc] = *(const uint4*)(whi + gb);
            *(uint4*)&Bl[row][scc] = *(const uint4*)(wlo + gb);
        }
        __syncthreads();

        bf16x8 ah[4], al[4], bh[4], bl[4];
        #pragma unroll
        for (int i = 0; i < 4; ++i) {
            ah[i] = *(const bf16x8*)&Ah[wm + i * 16 + fm][quad * 8];
            al[i] = *(const bf16x8*)&Al[wm + i * 16 + fm][quad * 8];
            bh[i] = *(const bf16x8*)&Bh[wn + i * 16 + fm][quad * 8];
            bl[i] = *(const bf16x8*)&Bl[wn + i * 16 + fm][quad * 8];
        }
        #pragma unroll
        for (int mi = 0; mi < 4; ++mi) {
            #pragma unroll
            for (int ni = 0; ni < 4; ++ni) {
                acc[mi][ni] = __builtin_amdgcn_mfma_f32_16x16x32_bf16(ah[mi], bh[ni], acc[mi][ni], 0, 0, 0);
                acc[mi][ni] = __builtin_amdgcn_mfma_f32_16x16x32_bf16(ah[mi], bl[ni], acc[mi][ni], 0, 0, 0);
                acc[mi][ni] = __builtin_amdgcn_mfma_f32_16x16x32_bf16(al[mi], bh[ni], acc[mi][ni], 0, 0, 0);
            }
        }
        __syncthreads();
    }

    const bool is_alpha = (n0 < D_);
    #pragma unroll
    for (int mi = 0; mi < 4; ++mi) {
        #pragma unroll
        for (int ni = 0; ni < 4; ++ni) {
            const int nglob = n0 + wn + ni * 16 + fm;   // C/D col = lane&15
            #pragma unroll
            for (int r = 0; r < 4; ++r) {
                const int mglob = m0 + wm + mi * 16 + quad * 4 + r;  // row=(lane>>4)*4+reg
                float z = acc[mi][ni][r];
                if (is_alpha) {
                    z += ba[nglob];
                    float s = 1.0f / (1.0f + __expf(-z));
                    h_ptr[(size_t)BD + (size_t)mglob * D_ + nglob] = s;  // alpha[t] at h slot t+1
                } else {
                    int nn = nglob - D_;
                    z += bv[nn];
                    out_ptr[(size_t)mglob * D_ + nn] = tanhf(z);         // v_raw[t] at out slot t
                }
            }
        }
    }
}

// ---------------- sequential self-gating scan ------------------------------
// reads alpha from h slot t+1 / v_raw from out slot t, overwrites in place.
__global__ __launch_bounds__(64) void scan_kernel(
    float* __restrict__ out_ptr, float* __restrict__ h_ptr,
    const float* __restrict__ h0, const float* __restrict__ d_g,
    const float* __restrict__ b_g)
{
    const int i = blockIdx.x * 64 + threadIdx.x;   // 0..BD-1
    const int d = i & (D_ - 1);
    const float dgv = d_g[d];
    const float bgv = b_g[d];
    float h = h0[i];
    h_ptr[i] = h;                                  // h[0]

    constexpr int PF = 8;                          // prefetch depth
    float abuf[PF], vbuf[PF];
    #pragma unroll
    for (int p = 0; p < PF; ++p) {
        abuf[p] = h_ptr[(size_t)(p + 1) * BD + i];
        vbuf[p] = out_ptr[(size_t)p * BD + i];
    }

    #pragma unroll 8
    for (int t = 0; t < T_; ++t) {
        const int s = t & (PF - 1);                // constant after unroll-8
        float a  = abuf[s];
        float vr = vbuf[s];
        const int tp = t + PF;
        if (tp < T_) {
            abuf[s] = h_ptr[(size_t)(tp + 1) * BD + i];
            vbuf[s] = out_ptr[(size_t)tp * BD + i];
        }
        float g = 1.0f / (1.0f + __expf(-(dgv * h + bgv)));
        float v = vr * g;
        h = a * h + (1.0f - a) * v;
        float sg = 1.0f / (1.0f + __expf(-h));
        out_ptr[(size_t)t * BD + i] = h * h * sg;
        h_ptr[(size_t)(t + 1) * BD + i] = h;
    }
}

// ---------------------------------------------------------------------------
extern "C" void kernel_launch(void* const* d_in, const int* in_sizes, int n_in,
                              void* d_out, int out_size, void* d_ws, size_t ws_size,
                              hipStream_t stream) {
    const float* x  = (const float*)d_in[0];
    const float* h0 = (const float*)d_in[1];
    const float* Wa = (const float*)d_in[2];
    const float* ba = (const float*)d_in[3];
    const float* Wx = (const float*)d_in[4];
    const float* bv = (const float*)d_in[5];
    const float* dg = (const float*)d_in[6];
    const float* bg = (const float*)d_in[7];

    float* out_ptr = (float*)d_out;                     // [T,B,D]
    float* h_ptr   = out_ptr + (size_t)T_ * BD;         // [T+1,B,D]

    // workspace layout: xhi, xlo [32768*1024] bf16; whi, wlo [2048*1024] bf16
    u16* xhi = (u16*)d_ws;
    u16* xlo = xhi + (size_t)MM * KK;
    u16* whi = xlo + (size_t)MM * KK;
    u16* wlo = whi + (size_t)NN * KK;
    // requires ws_size >= 2*MM*KK*2 + 2*NN*KK*2 = 142.6 MB

    int n4x = MM * KK / 4;                              // 8388608
    split_kernel<<<n4x / 256, 256, 0, stream>>>(x, xhi, xlo, n4x);
    int n4w = D_ * D_ / 4;                              // 262144
    split_kernel<<<n4w / 256, 256, 0, stream>>>(Wa, whi, wlo, n4w);
    split_kernel<<<n4w / 256, 256, 0, stream>>>(Wx, whi + (size_t)D_ * KK, wlo + (size_t)D_ * KK, n4w);

    dim3 grid(NN / BN, MM / BM);                        // (16, 256)
    gemm_dual<<<grid, 256, 0, stream>>>(xhi, xlo, whi, wlo, ba, bv, out_ptr, h_ptr);

    scan_kernel<<<BD / 64, 64, 0, stream>>>(out_ptr, h_ptr, h0, dg, bg);
}

// Round 2
// 1054.382 us; speedup vs baseline: 1.9167x; 1.9167x over previous
//
#include <hip/hip_runtime.h>

typedef unsigned short u16;
typedef unsigned int u32;

#define T_ 2048
#define B_ 16
#define D_ 1024
constexpr int MM = T_ * B_;     // 32768 GEMM rows
constexpr int KK = D_;          // 1024
constexpr int NN = 2 * D_;      // 2048 (alpha cols | v cols)
constexpr int BD = B_ * D_;     // 16384
constexpr int BM = 128, BN = 128, BK = 32;

typedef __bf16 bf16x8 __attribute__((ext_vector_type(8)));
typedef float f32x4 __attribute__((ext_vector_type(4)));

typedef __attribute__((address_space(3))) u32 lds_u32_t;
typedef __attribute__((address_space(1))) u32 gbl_u32_t;

__device__ __forceinline__ void gld16(void* lds, const void* g) {
    // async global->LDS, 16B per lane, dest = wave-uniform base + lane*16
    __builtin_amdgcn_global_load_lds((const gbl_u32_t*)g, (lds_u32_t*)lds, 16, 0, 0);
}

__device__ __forceinline__ float fast_sig(float x) {
    return __builtin_amdgcn_rcpf(1.0f + __expf(-x));
}

// ---------------- split fp32 -> bf16 hi/lo (truncation; lo corrects hi) ----
__device__ inline void split1(float f, u16& h, u16& l) {
    u32 u = __float_as_uint(f);
    h = (u16)(u >> 16);
    float fh = __uint_as_float(u & 0xffff0000u);
    float r = f - fh;                   // exact (low mantissa bits)
    l = (u16)(__float_as_uint(r) >> 16);
}

__global__ __launch_bounds__(256) void split_kernel(
    const float* __restrict__ src, u16* __restrict__ hi, u16* __restrict__ lo, int n4)
{
    int i = blockIdx.x * 256 + threadIdx.x;
    if (i >= n4) return;
    float4 v = ((const float4*)src)[i];
    u16 h0, h1, h2, h3, l0, l1, l2, l3;
    split1(v.x, h0, l0); split1(v.y, h1, l1);
    split1(v.z, h2, l2); split1(v.w, h3, l3);
    ushort4 hv; hv.x = h0; hv.y = h1; hv.z = h2; hv.w = h3;
    ushort4 lv; lv.x = l0; lv.y = l1; lv.z = l2; lv.w = l3;
    ((ushort4*)hi)[i] = hv;
    ((ushort4*)lo)[i] = lv;
}

// ---------------- fused dual GEMM: [32768,1024] x [2048,1024]^T ------------
// n<1024 -> sigmoid(.+b_alpha) = alpha  -> h region slot t+1
// n>=1024 -> tanh(.+b_v)       = v_raw  -> out region
__global__ __launch_bounds__(256) void gemm_dual(
    const u16* __restrict__ xhi, const u16* __restrict__ xlo,
    const u16* __restrict__ whi, const u16* __restrict__ wlo,
    const float* __restrict__ ba, const float* __restrict__ bv,
    float* __restrict__ out_ptr, float* __restrict__ h_ptr)
{
    __shared__ u16 Ah[BM][BK];   // 8 KB each, rows 64B, unpadded (gld16 needs this)
    __shared__ u16 Al[BM][BK];
    __shared__ u16 Bh[BN][BK];
    __shared__ u16 Bl[BN][BK];

    const int tid  = threadIdx.x;
    const int m0   = blockIdx.y * BM;
    const int n0   = blockIdx.x * BN;
    const int wave = tid >> 6, lane = tid & 63;
    const int wm = (wave & 1) << 6;     // wave's 64-row region for MFMA
    const int wn = (wave >> 1) << 6;    // wave's 64-col region
    const int fm = lane & 15, quad = lane >> 4;
    const int wb = wave << 5;           // staging: wave covers 32 rows (2 calls x 16)
    const int rl = lane >> 2;           // staging row within 16-row group
    const int cl = (lane & 3) << 3;     // staging col (elements), 16B per lane

    f32x4 acc[4][4] = {};

    for (int k0 = 0; k0 < KK; k0 += BK) {
        size_t ga = (size_t)(m0 + wb + rl) * KK + k0 + cl;
        size_t gb = (size_t)(n0 + wb + rl) * KK + k0 + cl;
        gld16(&Ah[wb][0],      xhi + ga);
        gld16(&Ah[wb + 16][0], xhi + ga + (size_t)16 * KK);
        gld16(&Al[wb][0],      xlo + ga);
        gld16(&Al[wb + 16][0], xlo + ga + (size_t)16 * KK);
        gld16(&Bh[wb][0],      whi + gb);
        gld16(&Bh[wb + 16][0], whi + gb + (size_t)16 * KK);
        gld16(&Bl[wb][0],      wlo + gb);
        gld16(&Bl[wb + 16][0], wlo + gb + (size_t)16 * KK);
        __syncthreads();   // drains vmcnt -> LDS data visible

        bf16x8 ah[4], al[4], bh[4], bl[4];
        #pragma unroll
        for (int i = 0; i < 4; ++i) {
            ah[i] = *(const bf16x8*)&Ah[wm + i * 16 + fm][quad * 8];
            al[i] = *(const bf16x8*)&Al[wm + i * 16 + fm][quad * 8];
            bh[i] = *(const bf16x8*)&Bh[wn + i * 16 + fm][quad * 8];
            bl[i] = *(const bf16x8*)&Bl[wn + i * 16 + fm][quad * 8];
        }
        #pragma unroll
        for (int mi = 0; mi < 4; ++mi) {
            #pragma unroll
            for (int ni = 0; ni < 4; ++ni) {
                acc[mi][ni] = __builtin_amdgcn_mfma_f32_16x16x32_bf16(ah[mi], bh[ni], acc[mi][ni], 0, 0, 0);
                acc[mi][ni] = __builtin_amdgcn_mfma_f32_16x16x32_bf16(ah[mi], bl[ni], acc[mi][ni], 0, 0, 0);
                acc[mi][ni] = __builtin_amdgcn_mfma_f32_16x16x32_bf16(al[mi], bh[ni], acc[mi][ni], 0, 0, 0);
            }
        }
        __syncthreads();
    }

    const bool is_alpha = (n0 < D_);
    #pragma unroll
    for (int mi = 0; mi < 4; ++mi) {
        #pragma unroll
        for (int ni = 0; ni < 4; ++ni) {
            const int nglob = n0 + wn + ni * 16 + fm;   // C/D col = lane&15
            #pragma unroll
            for (int r = 0; r < 4; ++r) {
                const int mglob = m0 + wm + mi * 16 + quad * 4 + r;  // row=(lane>>4)*4+reg
                float z = acc[mi][ni][r];
                if (is_alpha) {
                    z += ba[nglob];
                    float s = 1.0f / (1.0f + __expf(-z));
                    h_ptr[(size_t)BD + (size_t)mglob * D_ + nglob] = s;  // alpha[t] at h slot t+1
                } else {
                    int nn = nglob - D_;
                    z += bv[nn];
                    out_ptr[(size_t)mglob * D_ + nn] = tanhf(z);         // v_raw[t] at out slot t
                }
            }
        }
    }
}

// ---------------- sequential self-gating scan ------------------------------
// reads alpha from h slot t+1 / v_raw from out slot t, overwrites in place.
// Chunked PF-deep register prefetch: constant indices inside unrolled bodies,
// NO branches in the body -> buffers stay in VGPRs (R1 failure: dynamic index
// -> scratch -> 1300 cyc/iter).
__global__ __launch_bounds__(64) void scan_kernel(
    float* __restrict__ out_ptr, float* __restrict__ h_ptr,
    const float* __restrict__ h0, const float* __restrict__ d_g,
    const float* __restrict__ b_g)
{
    const int i = blockIdx.x * 64 + threadIdx.x;   // 0..BD-1
    const int d = i & (D_ - 1);
    const float dgv = d_g[d];
    const float bgv = b_g[d];
    float h = h0[i];
    h_ptr[i] = h;                                  // h[0]

    constexpr int PF = 16;
    const float* ap = h_ptr + BD + i;              // alpha[t] lives at h slot t+1
    const float* vp = out_ptr + i;                 // v_raw[t] at out slot t
    float* op = out_ptr + i;
    float* hp = h_ptr + BD + i;                    // h[t+1] target

    float abuf[PF], vbuf[PF];
    #pragma unroll
    for (int p = 0; p < PF; ++p) {
        abuf[p] = ap[(size_t)p * BD];
        vbuf[p] = vp[(size_t)p * BD];
    }

    int t = 0;
    for (int tc = 0; tc < T_ / PF - 1; ++tc) {     // 127 main chunks
        #pragma unroll
        for (int p = 0; p < PF; ++p) {
            float a  = abuf[p];
            float vr = vbuf[p];
            abuf[p] = ap[(size_t)(t + PF) * BD];   // unconditional prefetch
            vbuf[p] = vp[(size_t)(t + PF) * BD];
            float g = fast_sig(dgv * h + bgv);
            float v = vr * g;
            h = a * h + (1.0f - a) * v;
            float sg = fast_sig(h);
            __builtin_nontemporal_store(h * h * sg, op + (size_t)t * BD);
            __builtin_nontemporal_store(h, hp + (size_t)t * BD);
            ++t;
        }
    }
    #pragma unroll
    for (int p = 0; p < PF; ++p) {                 // tail chunk, no prefetch
        float a  = abuf[p];
        float vr = vbuf[p];
        float g = fast_sig(dgv * h + bgv);
        float v = vr * g;
        h = a * h + (1.0f - a) * v;
        float sg = fast_sig(h);
        __builtin_nontemporal_store(h * h * sg, op + (size_t)t * BD);
        __builtin_nontemporal_store(h, hp + (size_t)t * BD);
        ++t;
    }
}

// ---------------------------------------------------------------------------
extern "C" void kernel_launch(void* const* d_in, const int* in_sizes, int n_in,
                              void* d_out, int out_size, void* d_ws, size_t ws_size,
                              hipStream_t stream) {
    const float* x  = (const float*)d_in[0];
    const float* h0 = (const float*)d_in[1];
    const float* Wa = (const float*)d_in[2];
    const float* ba = (const float*)d_in[3];
    const float* Wx = (const float*)d_in[4];
    const float* bv = (const float*)d_in[5];
    const float* dg = (const float*)d_in[6];
    const float* bg = (const float*)d_in[7];

    float* out_ptr = (float*)d_out;                     // [T,B,D]
    float* h_ptr   = out_ptr + (size_t)T_ * BD;         // [T+1,B,D]

    // workspace layout: xhi, xlo [32768*1024] bf16; whi, wlo [2048*1024] bf16
    u16* xhi = (u16*)d_ws;
    u16* xlo = xhi + (size_t)MM * KK;
    u16* whi = xlo + (size_t)MM * KK;
    u16* wlo = whi + (size_t)NN * KK;
    // requires ws_size >= 2*MM*KK*2 + 2*NN*KK*2 = 142.6 MB

    int n4x = MM * KK / 4;                              // 8388608
    split_kernel<<<n4x / 256, 256, 0, stream>>>(x, xhi, xlo, n4x);
    int n4w = D_ * D_ / 4;                              // 262144
    split_kernel<<<n4w / 256, 256, 0, stream>>>(Wa, whi, wlo, n4w);
    split_kernel<<<n4w / 256, 256, 0, stream>>>(Wx, whi + (size_t)D_ * KK, wlo + (size_t)D_ * KK, n4w);

    dim3 grid(NN / BN, MM / BM);                        // (16, 256)
    gemm_dual<<<grid, 256, 0, stream>>>(xhi, xlo, whi, wlo, ba, bv, out_ptr, h_ptr);

    scan_kernel<<<BD / 64, 64, 0, stream>>>(out_ptr, h_ptr, h0, dg, bg);
}